// Round 6
// baseline (1052.897 us; speedup 1.0000x reference)
//
#include <hip/hip_runtime.h>

#define N_NODES 100000
#define N_EDGES 1600000
#define IN_F 128
#define H_F 64
#define C_F 16

#define BIN_SH 7
#define BIN_NODES 128          // 1 << BIN_SH
#define NBINS 782              // ceil(100000 / 128) == grid size
#define BCAP 2816              // fixed bin capacity (mean 2048, sigma 45 -> +17s)
#define PARTB 391              // partition blocks (4096 edges each, R2-proven)
#define NTILES 6250            // 16-node row tiles for gemm1
#define RMAXC 11               // ceil(BCAP / 256) records/thread in sort cache
#define AGG_STRIDE 36          // LDS agg tile row stride in words (144 B)

typedef __attribute__((ext_vector_type(8))) short bf16x8;  // 8 bf16 (4 VGPRs)
typedef __attribute__((ext_vector_type(4))) float f32x4;   // MFMA C/D

// fp32 -> bf16 round-to-nearest-even (finite inputs)
__device__ inline unsigned short f2bf(float f) {
  unsigned u = __float_as_uint(f);
  unsigned r = (u + 0x7fff + ((u >> 16) & 1)) >> 16;
  return (unsigned short)r;
}

// Persistent-grid barrier: co-residency guaranteed (4 blocks/CU by LDS,
// VGPR capped by launch_bounds; 782 <= 1024 slots). Device-scope acq/rel
// atomics + threadfence handle cross-XCD L2 non-coherence (Guideline 16).
__device__ inline void gridbar(int* c) {
  __threadfence();  // release: write back this XCD's L2
  __syncthreads();
  if (threadIdx.x == 0) {
    __hip_atomic_fetch_add(c, 1, __ATOMIC_ACQ_REL, __HIP_MEMORY_SCOPE_AGENT);
    while (__hip_atomic_load(c, __ATOMIC_ACQUIRE, __HIP_MEMORY_SCOPE_AGENT) <
           NBINS) {
      __builtin_amdgcn_s_sleep(2);
    }
  }
  __syncthreads();
  __threadfence();  // acquire: invalidate stale lines
}

// One 16-node GEMM1 row tile: H1b[rt*16..+16) = bf16(X @ W1) (R2-proven body)
__device__ inline void gemm1_tile(int rt, int lane, const short* ldsB,
                                  const float* __restrict__ X,
                                  unsigned short* __restrict__ H1b) {
  int node0 = rt * 16;
  int l = lane & 15, q = lane >> 4;
  const float* xp = X + (size_t)(node0 + l) * IN_F + q * 8;
  f32x4 acc[4] = {f32x4{0.f, 0.f, 0.f, 0.f}, f32x4{0.f, 0.f, 0.f, 0.f},
                  f32x4{0.f, 0.f, 0.f, 0.f}, f32x4{0.f, 0.f, 0.f, 0.f}};
#pragma unroll
  for (int s = 0; s < 4; ++s) {
    float4 x0 = *(const float4*)(xp + s * 32);
    float4 x1 = *(const float4*)(xp + s * 32 + 4);
    bf16x8 a;
    a[0] = f2bf(x0.x); a[1] = f2bf(x0.y); a[2] = f2bf(x0.z); a[3] = f2bf(x0.w);
    a[4] = f2bf(x1.x); a[5] = f2bf(x1.y); a[6] = f2bf(x1.z); a[7] = f2bf(x1.w);
#pragma unroll
    for (int c = 0; c < 4; ++c) {
      bf16x8 bb = *(const bf16x8*)&ldsB[(c * 4 + s) * 512 + lane * 8];
      acc[c] = __builtin_amdgcn_mfma_f32_16x16x32_bf16(a, bb, acc[c], 0, 0, 0);
    }
  }
  // C/D: col = lane&15 (feat), row = q*4 + reg (node)
#pragma unroll
  for (int c = 0; c < 4; ++c)
#pragma unroll
    for (int r = 0; r < 4; ++r)
      H1b[(size_t)(node0 + q * 4 + r) * H_F + c * 16 + l] = f2bf(acc[c][r]);
}

// ---------------- single persistent mega-kernel ---------------------------
// Phase A: gemm1 (all blocks) || partition edge-load + LDS hist (b<PARTB).
// Phase B: reserve (global atomics) + scatter records to ebin (b<PARTB).
// Phase C: per-bin counting sort (ebin -> LDS srt) + gather1 + bias/relu +
//          fused gemm2 -> H2b.  srt/h/sc stay in LDS.
// Phase D: gather2 straight from LDS-resident srt -> out.
// Grid-wide ordering via gridbar (3 barriers, counters memset pre-launch).
__global__ __launch_bounds__(256, 4) void gcn_mega(
    const int* __restrict__ src, const int* __restrict__ dst,
    const float* __restrict__ ew, const float* __restrict__ X,
    const float* __restrict__ W1, const float* __restrict__ b1,
    const float* __restrict__ W2, const float* __restrict__ b2,
    int* __restrict__ binCnt, int2* __restrict__ ebin,
    unsigned short* __restrict__ H1b, unsigned short* __restrict__ H2b,
    float* __restrict__ out, int* __restrict__ bar) {
  // LDS union (34928 B total -> 4 blocks/CU; grid 782 needs 3.06/CU):
  //   A/B: ldsB[0..16384) | hist[16384..19512) | base[19512..22640)
  //   C  : aggU[0..18432) | ldsW2[18432..20480) | cur[20480..20992)
  //   C,D: srt[22640..33904) | h[33904..34416) | sc[34416..34928)
  __shared__ __align__(16) char L[34928];
  short* ldsB = (short*)L;
  int* hist = (int*)(L + 16384);
  int* base = (int*)(L + 19512);
  unsigned* aggU = (unsigned*)L;
  short* ldsW2 = (short*)(L + 18432);
  int* cur = (int*)(L + 20480);
  unsigned* srt = (unsigned*)(L + 22640);
  int* h = (int*)(L + 33904);
  int* sc = (int*)(L + 34416);

  int b = blockIdx.x, tid = threadIdx.x;
  int wave = tid >> 6, lane = tid & 63;

  unsigned key[16], aux[16];  // partition records (live A -> B, b<PARTB only)

  // ======================= Phase A =======================
  if (b < PARTB) {
    for (int i = tid; i < NBINS; i += 256) hist[i] = 0;
  }
  // W1 fragment fill (all blocks)
  for (int idx = tid; idx < 16 * 512; idx += 256) {
    int frag = idx >> 9;    // c*4 + s
    int entry = idx & 511;  // lane*8 + j
    int ln = entry >> 3, j = entry & 7;
    int c = frag >> 2, s = frag & 3;
    int k = s * 32 + (ln >> 4) * 8 + j;
    int n = c * 16 + (ln & 15);
    ldsB[idx] = (short)f2bf(W1[k * H_F + n]);
  }
  __syncthreads();
  // gemm1: partition blocks do 4 tiles (1 rep), others 12 (3 reps)
  if (b < PARTB) {
    gemm1_tile(b * 4 + wave, lane, ldsB, X, H1b);  // rt in [0,1564)
  } else {
#pragma unroll
    for (int rep = 0; rep < 3; ++rep) {
      int rt = 1564 + (b - PARTB) * 12 + rep * 4 + wave;
      if (rt < NTILES) gemm1_tile(rt, lane, ldsB, X, H1b);
    }
  }
  // partition: load 4096 edges (16/thread) to regs + LDS hist
  if (b < PARTB) {
    int i0 = b * 1024;  // int4 index base
    int iHi = i0 + 1024;
    if (iHi > N_EDGES / 4) iHi = N_EDGES / 4;
    const int4* d4p = (const int4*)dst;
    const int4* s4p = (const int4*)src;
    const float4* w4p = (const float4*)ew;
#pragma unroll
    for (int it = 0; it < 4; ++it) {
      int i = i0 + it * 256 + tid;
      if (i < iHi) {
        int4 d = d4p[i];
        int4 s = s4p[i];
        float4 w = w4p[i];
#pragma unroll
        for (int j = 0; j < 4; ++j) {
          int dd = (&d.x)[j];
          int ss = (&s.x)[j];
          float ww = (&w.x)[j];
          int bb = dd >> BIN_SH;
          unsigned wf = (unsigned)(ww * 32767.0f + 0.5f);
          key[it * 4 + j] =
              (unsigned)ss | ((unsigned)(dd & (BIN_NODES - 1)) << 17);
          aux[it * 4 + j] = wf | ((unsigned)bb << 15);
          atomicAdd(&hist[bb], 1);
        }
      }
    }
  }
  gridbar(&bar[0]);

  // ======================= Phase B =======================
  if (b < PARTB) {
    for (int t = tid; t < NBINS; t += 256)
      base[t] = hist[t] ? atomicAdd(&binCnt[t], hist[t]) : 0;
    __syncthreads();
    int i0 = b * 1024;
    int iHi = i0 + 1024;
    if (iHi > N_EDGES / 4) iHi = N_EDGES / 4;
#pragma unroll
    for (int it = 0; it < 4; ++it) {
      int i = i0 + it * 256 + tid;
      if (i < iHi) {
        int pos[4];
#pragma unroll
        for (int j = 0; j < 4; ++j)
          pos[j] = atomicAdd(&base[aux[it * 4 + j] >> 15], 1);
#pragma unroll
        for (int j = 0; j < 4; ++j)
          ebin[(size_t)(aux[it * 4 + j] >> 15) * BCAP + pos[j]] =
              make_int2((int)key[it * 4 + j], (int)(aux[it * 4 + j] & 0x7FFF));
      }
    }
  }
  gridbar(&bar[1]);

  // ======================= Phase C =======================
  {
    // W2 swizzle fill
    for (int idx = tid; idx < 1024; idx += 256) {
      int sfrag = idx >> 9;
      int entry = idx & 511;
      int ln = entry >> 3, j = entry & 7;
      int k = sfrag * 32 + (ln >> 4) * 8 + j;
      int c = ln & 15;
      ldsW2[idx] = (short)f2bf(W2[k * C_F + c]);
    }
    if (tid < BIN_NODES) h[tid] = 0;
    __syncthreads();
    int lo = b * BCAP;
    int cnt = binCnt[b];
    unsigned rk[RMAXC];
    int rd[RMAXC];
    int rn = 0;
#pragma unroll
    for (int j = 0; j < RMAXC; ++j) {
      int e = j * 256 + tid;
      if (e < cnt) {
        int2 r = ebin[lo + e];
        int dl = (((unsigned)r.x) >> 17) & (BIN_NODES - 1);
        rk[j] = ((unsigned)r.x & 0x1FFFF) | ((unsigned)r.y << 17);
        rd[j] = dl;
        atomicAdd(&h[dl], 1);
        rn = j + 1;
      }
    }
    __syncthreads();
    if (tid < BIN_NODES) sc[tid] = h[tid];
    __syncthreads();
#pragma unroll
    for (int d = 1; d < BIN_NODES; d <<= 1) {
      int t = 0;
      if (tid < BIN_NODES && tid >= d) t = sc[tid - d];
      __syncthreads();
      if (tid < BIN_NODES) sc[tid] += t;
      __syncthreads();
    }
    if (tid < BIN_NODES) cur[tid] = sc[tid] - h[tid];
    __syncthreads();
#pragma unroll
    for (int j = 0; j < RMAXC; ++j)
      if (j < rn) {
        int pos = atomicAdd(&cur[rd[j]], 1);
        srt[pos] = rk[j];
      }
    __syncthreads();
    // ---- gather1: 4 waves x 32 nodes ----
    const uint2* H1q = (const uint2*)H1b;
    int g = lane >> 4, li = lane & 15;
    const float wsc = 1.0f / 32767.0f;
    float bb0 = b1[li * 4], bb1 = b1[li * 4 + 1];
    float bb2 = b1[li * 4 + 2], bb3 = b1[li * 4 + 3];
    for (int k = 0; k < 32; ++k) {
      int nl = wave * 32 + k;
      int n = (b << BIN_SH) + nl;
      if (n >= N_NODES) break;
      int e1 = sc[nl], e0 = e1 - h[nl];
      f32x4 a0 = {0.f, 0.f, 0.f, 0.f}, a1 = {0.f, 0.f, 0.f, 0.f};
      f32x4 a2 = {0.f, 0.f, 0.f, 0.f}, a3 = {0.f, 0.f, 0.f, 0.f};
      int i = e0;
      for (; i + 15 < e1; i += 16) {
        unsigned r0 = srt[i + g];
        unsigned r1 = srt[i + 4 + g];
        unsigned r2 = srt[i + 8 + g];
        unsigned r3 = srt[i + 12 + g];
        uint2 v0 = H1q[(r0 & 0x1FFFF) * (H_F / 4) + li];
        uint2 v1 = H1q[(r1 & 0x1FFFF) * (H_F / 4) + li];
        uint2 v2 = H1q[(r2 & 0x1FFFF) * (H_F / 4) + li];
        uint2 v3 = H1q[(r3 & 0x1FFFF) * (H_F / 4) + li];
        float w0 = (float)(r0 >> 17) * wsc, w1 = (float)(r1 >> 17) * wsc;
        float w2 = (float)(r2 >> 17) * wsc, w3 = (float)(r3 >> 17) * wsc;
        a0[0] += __uint_as_float(v0.x << 16) * w0;
        a0[1] += __uint_as_float(v0.x & 0xFFFF0000u) * w0;
        a0[2] += __uint_as_float(v0.y << 16) * w0;
        a0[3] += __uint_as_float(v0.y & 0xFFFF0000u) * w0;
        a1[0] += __uint_as_float(v1.x << 16) * w1;
        a1[1] += __uint_as_float(v1.x & 0xFFFF0000u) * w1;
        a1[2] += __uint_as_float(v1.y << 16) * w1;
        a1[3] += __uint_as_float(v1.y & 0xFFFF0000u) * w1;
        a2[0] += __uint_as_float(v2.x << 16) * w2;
        a2[1] += __uint_as_float(v2.x & 0xFFFF0000u) * w2;
        a2[2] += __uint_as_float(v2.y << 16) * w2;
        a2[3] += __uint_as_float(v2.y & 0xFFFF0000u) * w2;
        a3[0] += __uint_as_float(v3.x << 16) * w3;
        a3[1] += __uint_as_float(v3.x & 0xFFFF0000u) * w3;
        a3[2] += __uint_as_float(v3.y << 16) * w3;
        a3[3] += __uint_as_float(v3.y & 0xFFFF0000u) * w3;
      }
      for (; i + 3 < e1; i += 4) {
        unsigned r0 = srt[i + g];
        uint2 v0 = H1q[(r0 & 0x1FFFF) * (H_F / 4) + li];
        float w0 = (float)(r0 >> 17) * wsc;
        a0[0] += __uint_as_float(v0.x << 16) * w0;
        a0[1] += __uint_as_float(v0.x & 0xFFFF0000u) * w0;
        a0[2] += __uint_as_float(v0.y << 16) * w0;
        a0[3] += __uint_as_float(v0.y & 0xFFFF0000u) * w0;
      }
      if (i + g < e1) {
        unsigned r0 = srt[i + g];
        uint2 v0 = H1q[(r0 & 0x1FFFF) * (H_F / 4) + li];
        float w0 = (float)(r0 >> 17) * wsc;
        a1[0] += __uint_as_float(v0.x << 16) * w0;
        a1[1] += __uint_as_float(v0.x & 0xFFFF0000u) * w0;
        a1[2] += __uint_as_float(v0.y << 16) * w0;
        a1[3] += __uint_as_float(v0.y & 0xFFFF0000u) * w0;
      }
      f32x4 a = (a0 + a1) + (a2 + a3);
#pragma unroll
      for (int c = 0; c < 4; ++c) {
        a[c] += __shfl_xor(a[c], 16, 64);
        a[c] += __shfl_xor(a[c], 32, 64);
      }
      if (g == 0) {
        float r0 = fmaxf(a[0] + bb0, 0.f);
        float r1 = fmaxf(a[1] + bb1, 0.f);
        float r2 = fmaxf(a[2] + bb2, 0.f);
        float r3 = fmaxf(a[3] + bb3, 0.f);
        unsigned p0 = (unsigned)f2bf(r0) | ((unsigned)f2bf(r1) << 16);
        unsigned p1 = (unsigned)f2bf(r2) | ((unsigned)f2bf(r3) << 16);
        *(uint2*)&aggU[nl * AGG_STRIDE + li * 2] = make_uint2(p0, p1);
      }
    }
    __syncthreads();
    // ---- fused gemm2: wave covers 32 nodes in 2 reps ----
    int l = lane & 15, q = lane >> 4;
#pragma unroll
    for (int rep = 0; rep < 2; ++rep) {
      int nl0 = wave * 32 + rep * 16;
      f32x4 acc = {0.f, 0.f, 0.f, 0.f};
#pragma unroll
      for (int s = 0; s < 2; ++s) {
        bf16x8 afr =
            *(const bf16x8*)&aggU[(nl0 + l) * AGG_STRIDE + s * 16 + q * 4];
        bf16x8 bfr = *(const bf16x8*)&ldsW2[s * 512 + lane * 8];
        acc = __builtin_amdgcn_mfma_f32_16x16x32_bf16(afr, bfr, acc, 0, 0, 0);
      }
      int node0 = (b << BIN_SH) + nl0;
#pragma unroll
      for (int r = 0; r < 4; ++r) {
        int n = node0 + q * 4 + r;
        if (n < N_NODES) H2b[(size_t)n * C_F + l] = f2bf(acc[r]);
      }
    }
  }
  gridbar(&bar[2]);

  // ======================= Phase D =======================
  {
    const uint2* H2q = (const uint2*)H2b;
    int g = lane >> 2, li = lane & 3;
    const float wsc = 1.0f / 32767.0f;
    float bb0 = b2[li * 4], bb1 = b2[li * 4 + 1];
    float bb2 = b2[li * 4 + 2], bb3 = b2[li * 4 + 3];
    for (int k = 0; k < 32; ++k) {
      int nl = wave * 32 + k;
      int n = (b << BIN_SH) + nl;
      if (n >= N_NODES) break;
      int e1 = sc[nl], e0 = e1 - h[nl];
      f32x4 a0 = {0.f, 0.f, 0.f, 0.f};
      int i = e0;
      for (; i + 15 < e1; i += 16) {
        unsigned r0 = srt[i + g];
        uint2 v0 = H2q[(r0 & 0x1FFFF) * (C_F / 4) + li];
        float w0 = (float)(r0 >> 17) * wsc;
        a0[0] += __uint_as_float(v0.x << 16) * w0;
        a0[1] += __uint_as_float(v0.x & 0xFFFF0000u) * w0;
        a0[2] += __uint_as_float(v0.y << 16) * w0;
        a0[3] += __uint_as_float(v0.y & 0xFFFF0000u) * w0;
      }
      if (i + g < e1) {
        unsigned r0 = srt[i + g];
        uint2 v0 = H2q[(r0 & 0x1FFFF) * (C_F / 4) + li];
        float w0 = (float)(r0 >> 17) * wsc;
        a0[0] += __uint_as_float(v0.x << 16) * w0;
        a0[1] += __uint_as_float(v0.x & 0xFFFF0000u) * w0;
        a0[2] += __uint_as_float(v0.y << 16) * w0;
        a0[3] += __uint_as_float(v0.y & 0xFFFF0000u) * w0;
      }
#pragma unroll
      for (int c = 0; c < 4; ++c) {
        a0[c] += __shfl_xor(a0[c], 4, 64);
        a0[c] += __shfl_xor(a0[c], 8, 64);
        a0[c] += __shfl_xor(a0[c], 16, 64);
        a0[c] += __shfl_xor(a0[c], 32, 64);
      }
      if (g == 0) {
        float4 o;
        o.x = a0[0] + bb0;
        o.y = a0[1] + bb1;
        o.z = a0[2] + bb2;
        o.w = a0[3] + bb3;
        *(float4*)&out[(size_t)n * C_F + li * 4] = o;
      }
    }
  }
}

extern "C" void kernel_launch(void* const* d_in, const int* in_sizes, int n_in,
                              void* d_out, int out_size, void* d_ws,
                              size_t ws_size, hipStream_t stream) {
  const float* X  = (const float*)d_in[0];
  const float* ew = (const float*)d_in[1];
  const float* W1 = (const float*)d_in[2];
  const float* b1 = (const float*)d_in[3];
  const float* W2 = (const float*)d_in[4];
  const float* b2 = (const float*)d_in[5];
  const int* src  = (const int*)d_in[6];
  const int* dst  = (const int*)d_in[7];
  float* out = (float*)d_out;

  // Workspace (~33.6 MB):
  //   H1b bf16 [N x 64] 12.8 MB
  //   H2b bf16 [N x 16]  3.2 MB
  //   ebin int2 [NBINS x BCAP] 17.6 MB
  //   binCnt int [NBINS] + bar int [4]  (zeroed by the memset below)
  unsigned short* H1b = (unsigned short*)d_ws;
  unsigned short* H2b = H1b + (size_t)N_NODES * H_F;
  int2* ebin  = (int2*)(H2b + (size_t)N_NODES * C_F);
  int* binCnt = (int*)(ebin + (size_t)NBINS * BCAP);
  int* bar    = binCnt + NBINS;

  hipMemsetAsync(binCnt, 0, (NBINS + 4) * sizeof(int), stream);
  gcn_mega<<<NBINS, 256, 0, stream>>>(src, dst, ew, X, W1, b1, W2, b2, binCnt,
                                      ebin, H1b, H2b, out, bar);
}